// Round 1
// baseline (97.840 us; speedup 1.0000x reference)
//
#include <hip/hip_runtime.h>

#define HW_ELEMS (512 * 512)        // elements per (n,c) channel
#define NC 192                      // 64 * 3 channels
#define EPS 1e-8f

// One block per (n,c) channel. 1024 threads, each reads 64 float4 coalesced.
__global__ __launch_bounds__(1024) void instnorm_stats(
    const float* __restrict__ in, float2* __restrict__ stats)
{
    const int c = blockIdx.x;
    const float4* p = reinterpret_cast<const float4*>(in) + (size_t)c * (HW_ELEMS / 4);
    const int t = threadIdx.x;

    float sum = 0.f, sumsq = 0.f;
#pragma unroll
    for (int k = 0; k < HW_ELEMS / 4 / 1024; ++k) {   // 64 iterations
        float4 v = p[t + k * 1024];
        sum   += (v.x + v.y) + (v.z + v.w);
        sumsq += (v.x * v.x + v.y * v.y) + (v.z * v.z + v.w * v.w);
    }

    // wave (64-lane) reduction
#pragma unroll
    for (int off = 32; off > 0; off >>= 1) {
        sum   += __shfl_down(sum, off, 64);
        sumsq += __shfl_down(sumsq, off, 64);
    }

    __shared__ float s_sum[16];
    __shared__ float s_sq[16];
    const int wave = t >> 6;
    const int lane = t & 63;
    if (lane == 0) { s_sum[wave] = sum; s_sq[wave] = sumsq; }
    __syncthreads();

    if (t == 0) {
        float S = 0.f, Q = 0.f;
#pragma unroll
        for (int w = 0; w < 16; ++w) { S += s_sum[w]; Q += s_sq[w]; }
        const float n = (float)HW_ELEMS;
        float mean = S / n;
        float var  = (Q - S * S / n) / (n - 1.0f);   // unbiased (ddof=1)
        if (var < 0.f) var = 0.f;
        float rstd = 1.0f / (sqrtf(var) + EPS);
        stats[c] = make_float2(mean, rstd);
    }
}

// One float4 per thread. 65536 float4 per channel -> channel = i4 >> 16.
__global__ __launch_bounds__(256) void instnorm_apply(
    const float* __restrict__ in, float* __restrict__ out,
    const float2* __restrict__ stats)
{
    const size_t i4 = (size_t)blockIdx.x * 256 + threadIdx.x;
    const int c = (int)(i4 >> 16);                 // uniform within a block
    const float2 ms = stats[c];                    // (mean, rstd)
    float4 v = reinterpret_cast<const float4*>(in)[i4];
    float4 r;
    r.x = (v.x - ms.x) * ms.y;
    r.y = (v.y - ms.x) * ms.y;
    r.z = (v.z - ms.x) * ms.y;
    r.w = (v.w - ms.x) * ms.y;
    reinterpret_cast<float4*>(out)[i4] = r;
}

extern "C" void kernel_launch(void* const* d_in, const int* in_sizes, int n_in,
                              void* d_out, int out_size, void* d_ws, size_t ws_size,
                              hipStream_t stream) {
    const float* in = (const float*)d_in[0];
    float* out = (float*)d_out;
    float2* stats = (float2*)d_ws;   // 192 * 8 bytes

    instnorm_stats<<<NC, 1024, 0, stream>>>(in, stats);

    const size_t total4 = (size_t)NC * (HW_ELEMS / 4);   // 12,582,912 float4
    instnorm_apply<<<(int)(total4 / 256), 256, 0, stream>>>(in, out, stats);
}

// Round 3
// 91.076 us; speedup vs baseline: 1.0743x; 1.0743x over previous
//
#include <hip/hip_runtime.h>

#define HW_ELEMS (512 * 512)        // elements per (n,c) channel
#define HW4      (HW_ELEMS / 4)     // 65536 float4 per channel
#define NC 192                      // 64 * 3 channels
#define BPC 8                       // stats blocks per channel
#define EPS 1e-8f

typedef float fx4 __attribute__((ext_vector_type(4)));   // clang-native vec4

// Partial stats: 8 blocks per channel, 256 threads each, 32 float4 per thread.
__global__ __launch_bounds__(256) void instnorm_partial(
    const float* __restrict__ in, float2* __restrict__ partials)
{
    const int c = blockIdx.x >> 3;         // channel
    const int b = blockIdx.x & (BPC - 1);  // sub-block within channel
    const fx4* p = reinterpret_cast<const fx4*>(in)
                 + (size_t)c * HW4 + (size_t)b * (HW4 / BPC);
    const int t = threadIdx.x;

    float sum = 0.f, sumsq = 0.f;
#pragma unroll
    for (int k = 0; k < HW4 / BPC / 256; ++k) {   // 32 iterations
        fx4 v = p[t + k * 256];
        sum   += (v.x + v.y) + (v.z + v.w);
        sumsq += (v.x * v.x + v.y * v.y) + (v.z * v.z + v.w * v.w);
    }

    // wave (64-lane) reduction
#pragma unroll
    for (int off = 32; off > 0; off >>= 1) {
        sum   += __shfl_down(sum, off, 64);
        sumsq += __shfl_down(sumsq, off, 64);
    }

    __shared__ float s_sum[4];
    __shared__ float s_sq[4];
    const int wave = t >> 6;
    if ((t & 63) == 0) { s_sum[wave] = sum; s_sq[wave] = sumsq; }
    __syncthreads();

    if (t == 0) {
        float S = s_sum[0] + s_sum[1] + s_sum[2] + s_sum[3];
        float Q = s_sq[0] + s_sq[1] + s_sq[2] + s_sq[3];
        partials[blockIdx.x] = make_float2(S, Q);
    }
}

// Apply: one float4 per thread; 256 blocks per channel (65536 float4 / 256).
// Each block recomputes (mean, rstd) from the channel's 8 partials (uniform,
// L2-resident loads — negligible).
__global__ __launch_bounds__(256) void instnorm_apply(
    const float* __restrict__ in, float* __restrict__ out,
    const float2* __restrict__ partials)
{
    const int c = blockIdx.x >> 8;                 // 256 blocks per channel
    float S = 0.f, Q = 0.f;
#pragma unroll
    for (int b = 0; b < BPC; ++b) {
        float2 pq = partials[c * BPC + b];
        S += pq.x; Q += pq.y;
    }
    const float n = (float)HW_ELEMS;
    float mean = S / n;
    float var  = (Q - S * S / n) / (n - 1.0f);     // unbiased (ddof=1)
    if (var < 0.f) var = 0.f;
    float rstd = 1.0f / (sqrtf(var) + EPS);

    const size_t i4 = (size_t)blockIdx.x * 256 + threadIdx.x;
    fx4 v = reinterpret_cast<const fx4*>(in)[i4];
    fx4 r;
    r.x = (v.x - mean) * rstd;
    r.y = (v.y - mean) * rstd;
    r.z = (v.z - mean) * rstd;
    r.w = (v.w - mean) * rstd;
    __builtin_nontemporal_store(r, reinterpret_cast<fx4*>(out) + i4);
}

extern "C" void kernel_launch(void* const* d_in, const int* in_sizes, int n_in,
                              void* d_out, int out_size, void* d_ws, size_t ws_size,
                              hipStream_t stream) {
    const float* in = (const float*)d_in[0];
    float* out = (float*)d_out;
    float2* partials = (float2*)d_ws;   // NC * BPC * 8 bytes = 12 KiB

    instnorm_partial<<<NC * BPC, 256, 0, stream>>>(in, partials);

    const size_t total4 = (size_t)NC * HW4;        // 12,582,912 float4
    instnorm_apply<<<(int)(total4 / 256), 256, 0, stream>>>(in, out, partials);
}